// Round 8
// baseline (164.042 us; speedup 1.0000x reference)
//
#include <hip/hip_runtime.h>

#define E_DIM 1024
#define NHEAD 16
#define HDIM 64
#define SEQ 2048
#define NBATCH 2
#define WIN 256
#define MTOK (NBATCH * SEQ) // 4096
#define BKT 32              // K per pipeline tile
#define NT (E_DIM / BKT)    // 32 tiles

typedef __attribute__((ext_vector_type(4))) float f32x4;
typedef __attribute__((ext_vector_type(8))) short short8;
typedef __attribute__((ext_vector_type(4))) unsigned short u16x4;

#define AS1 __attribute__((address_space(1)))
#define AS3 __attribute__((address_space(3)))

__device__ __forceinline__ void gll16(const void* g, void* l) {
    __builtin_amdgcn_global_load_lds((const AS1 void*)g, (AS3 void*)l, 16, 0, 0);
}

__device__ __forceinline__ unsigned short f2bf(float f) {
    union { float f; unsigned u; } a; a.f = f;
    unsigned r = a.u + 0x7fffu + ((a.u >> 16) & 1u);
    return (unsigned short)(r >> 16);
}

// ---------------- fused fp32 -> bf16 conversion: x (4 segs) + 4 weights ----------------
__global__ __launch_bounds__(256) void conv_all(const float* __restrict__ x,
        const float* __restrict__ w0, const float* __restrict__ w1,
        const float* __restrict__ w2, const float* __restrict__ w3,
        unsigned short* __restrict__ xo,
        unsigned short* __restrict__ o0, unsigned short* __restrict__ o1,
        unsigned short* __restrict__ o2, unsigned short* __restrict__ o3) {
    const int seg = blockIdx.y;   // 0..3: x quarters; 4..7: weights
    const float* src;
    unsigned short* dst;
    if (seg < 4) { src = x + (size_t)seg * 1048576; dst = xo + (size_t)seg * 1048576; }
    else {
        src = (seg == 4) ? w0 : (seg == 5) ? w1 : (seg == 6) ? w2 : w3;
        dst = (seg == 4) ? o0 : (seg == 5) ? o1 : (seg == 6) ? o2 : o3;
    }
    int i = blockIdx.x * 256 + threadIdx.x;
    float4 v = ((const float4*)src)[i];
    u16x4 o;
    o[0] = f2bf(v.x); o[1] = f2bf(v.y); o[2] = f2bf(v.z); o[3] = f2bf(v.w);
    ((u16x4*)dst)[i] = o;
}

// ---------------- QKV GEMM: m97 geometry — 128x128, 4 waves, 32KB dbuf, 3 blocks/CU ----------------
// Per K-step: __syncthreads (drains stage(t) for all waves + frees buf for stage(t+1)),
// stage(t+1) into buf[(t+1)&1], 8 ds_read_b128, 16 MFMA. Inter-block overlap hides stalls.
__global__ __launch_bounds__(256, 3) void gemm97_qkv(const unsigned short* __restrict__ xb,
        const unsigned short* __restrict__ wqb, const unsigned short* __restrict__ wkb,
        const unsigned short* __restrict__ wvb,
        const float* __restrict__ bq, const float* __restrict__ bk, const float* __restrict__ bv,
        unsigned short* __restrict__ qo, unsigned short* __restrict__ ko,
        unsigned short* __restrict__ vTo) {
    __shared__ char lds[32768];           // 2 slots x (A 8KB + B 8KB)
    const int tid = threadIdx.x;
    const int w = tid >> 6, l = tid & 63;
    const int r16 = l & 15, kq = l >> 4;
    const int wr = w >> 1, wc = w & 1;    // 2x2 waves, each 64x64 out
    const int m0 = blockIdx.x * 128;
    const int by = blockIdx.y;            // 0..23
    const int mat = by >> 3;              // 0:Q 1:K 2:V
    const int nb = (by & 7) * 128;
    const unsigned short* Bw = (mat == 0) ? wqb : (mat == 1) ? wkb : wvb;

    // staging: per round (2 per panel), 4 waves x 1KB cover 64 rows; lane row = tid>>2
    const int srow = tid >> 2;            // 0..63
    const int sslot = tid & 3;
    const int fsw = (srow >> 1) & 3;      // (row>>1)&3 — same for row and row+64
    const int gslot = (sslot ^ fsw) * 8;  // pre-swizzled source slot (elements)
    const unsigned short* aSrc0 = xb + (size_t)(m0 + srow) * E_DIM + gslot;
    const unsigned short* aSrc1 = aSrc0 + (size_t)64 * E_DIM;
    const unsigned short* bSrc0 = Bw + (size_t)(nb + srow) * E_DIM + gslot;
    const unsigned short* bSrc1 = bSrc0 + (size_t)64 * E_DIM;
    const int dstOff = w * 1024;          // wave-uniform chunk base (bytes)

#define STAGE(t) { char* a_ = lds + ((t) & 1) * 16384 + dstOff; \
                   char* b_ = a_ + 8192; \
                   gll16(aSrc0 + (t) * BKT, a_); gll16(aSrc1 + (t) * BKT, a_ + 4096); \
                   gll16(bSrc0 + (t) * BKT, b_); gll16(bSrc1 + (t) * BKT, b_ + 4096); }

    f32x4 acc[4][4];
    #pragma unroll
    for (int m = 0; m < 4; ++m)
        #pragma unroll
        for (int n = 0; n < 4; ++n)
            acc[m][n] = (f32x4){0.f, 0.f, 0.f, 0.f};

    STAGE(0);

    const int fs = (r16 >> 1) & 3;        // read-side swizzle, frag-row-independent
    const int rdoff = (kq ^ fs) * 16;

    for (int t = 0; t < NT; ++t) {
        __syncthreads();                  // implicit vmcnt(0): stage(t) landed for ALL waves;
                                          // also orders stage(t+1) writes after tile t-1 reads
        if (t + 1 < NT) STAGE(t + 1);
        char* la = lds + (t & 1) * 16384;
        char* lb = la + 8192;
        short8 af[4], bfr[4];
        #pragma unroll
        for (int m = 0; m < 4; ++m)
            af[m] = *(const short8*)(la + (wr * 64 + m * 16 + r16) * 64 + rdoff);
        #pragma unroll
        for (int n = 0; n < 4; ++n)
            bfr[n] = *(const short8*)(lb + (wc * 64 + n * 16 + r16) * 64 + rdoff);
        __builtin_amdgcn_s_setprio(1);
        #pragma unroll
        for (int m = 0; m < 4; ++m)
            #pragma unroll
            for (int n = 0; n < 4; ++n)
                acc[m][n] = __builtin_amdgcn_mfma_f32_16x16x32_bf16(af[m], bfr[n], acc[m][n], 0, 0, 0);
        __builtin_amdgcn_s_setprio(0);
    }
#undef STAGE

    const float* bias = (mat == 0) ? bq : (mat == 1) ? bk : bv;
    const float scale = (mat == 0) ? 0.125f : 1.0f;   // D^-0.5 folded into Q
    #pragma unroll
    for (int n = 0; n < 4; ++n) {
        int e = nb + wc * 64 + n * 16 + r16;
        float bb = bias[e];
        int h = e >> 6, d = e & 63;
        #pragma unroll
        for (int m = 0; m < 4; ++m) {
            int tok = m0 + wr * 64 + m * 16 + kq * 4;
            int b = tok >> 11, s = tok & (SEQ - 1);
            if (mat == 2) {
                u16x4 o;
                #pragma unroll
                for (int r = 0; r < 4; ++r) o[r] = f2bf(acc[m][n][r] + bb);
                *(u16x4*)(vTo + ((size_t)(b * NHEAD + h) * HDIM + d) * SEQ + s) = o;
            } else {
                unsigned short* dst = (mat == 0) ? qo : ko;
                #pragma unroll
                for (int r = 0; r < 4; ++r) {
                    float val = (acc[m][n][r] + bb) * scale;
                    dst[((size_t)(b * NHEAD + h) * SEQ + s + r) * HDIM + d] = f2bf(val);
                }
            }
        }
    }
}

// ---------------- output projection: 128x128, 4 waves, 1 phase/tile, ledgered (r7, passed) ----------------
__global__ __launch_bounds__(256, 2) void gemm_out(const unsigned short* __restrict__ yb,
        const unsigned short* __restrict__ wob, const float* __restrict__ bo,
        float* __restrict__ out) {
    __shared__ char lds[65536];
    const int tid = threadIdx.x;
    const int w = tid >> 6, l = tid & 63;
    const int r16 = l & 15, kq = l >> 4;
    const int wr = w >> 1, wc = w & 1;
    const int m0 = blockIdx.x * 128;
    const int n0 = blockIdx.y * 128;

    const int srow = tid >> 2;
    const int sslot = tid & 3;
    const int fsw = (srow >> 1) & 3;
    const int gslot = (sslot ^ fsw) * 8;
    const unsigned short* aSrc0 = yb + (size_t)(m0 + srow) * E_DIM + gslot;
    const unsigned short* aSrc1 = aSrc0 + (size_t)64 * E_DIM;
    const unsigned short* bSrc0 = wob + (size_t)(n0 + srow) * E_DIM + gslot;
    const unsigned short* bSrc1 = bSrc0 + (size_t)64 * E_DIM;
    const int dstOff = w * 1024;

#define STAGE_A(t) { char* d_ = lds + ((t) & 3) * 16384 + dstOff; \
                     gll16(aSrc0 + (t) * BKT, d_); gll16(aSrc1 + (t) * BKT, d_ + 4096); }
#define STAGE_B(t) { char* d_ = lds + ((t) & 3) * 16384 + 8192 + dstOff; \
                     gll16(bSrc0 + (t) * BKT, d_); gll16(bSrc1 + (t) * BKT, d_ + 4096); }

    f32x4 acc[4][4];
    #pragma unroll
    for (int m = 0; m < 4; ++m)
        #pragma unroll
        for (int n = 0; n < 4; ++n)
            acc[m][n] = (f32x4){0.f, 0.f, 0.f, 0.f};

    STAGE_A(0); STAGE_B(0); STAGE_A(1); STAGE_B(1);
    asm volatile("s_waitcnt vmcnt(4)" ::: "memory");
    __builtin_amdgcn_sched_barrier(0);
    __builtin_amdgcn_s_barrier();

    const int fs = (r16 >> 1) & 3;
    const int rdoff = (kq ^ fs) * 16;

    for (int t = 0; t < NT; ++t) {
        char* la = lds + (t & 3) * 16384;
        char* lb = la + 8192;
        short8 bfr[4], af[4];
        #pragma unroll
        for (int n = 0; n < 4; ++n)
            bfr[n] = *(const short8*)(lb + (wc * 64 + n * 16 + r16) * 64 + rdoff);
        #pragma unroll
        for (int m = 0; m < 4; ++m)
            af[m] = *(const short8*)(la + (wr * 64 + m * 16 + r16) * 64 + rdoff);
        if (t + 2 < NT) { STAGE_A(t + 2); STAGE_B(t + 2); }
        __builtin_amdgcn_s_barrier();
        asm volatile("s_waitcnt lgkmcnt(0)" ::: "memory");
        __builtin_amdgcn_sched_barrier(0);
        __builtin_amdgcn_s_setprio(1);
        #pragma unroll
        for (int m = 0; m < 4; ++m)
            #pragma unroll
            for (int n = 0; n < 4; ++n)
                acc[m][n] = __builtin_amdgcn_mfma_f32_16x16x32_bf16(af[m], bfr[n], acc[m][n], 0, 0, 0);
        __builtin_amdgcn_s_setprio(0);
        if (t < NT - 1) {
            if (t < NT - 2) { asm volatile("s_waitcnt vmcnt(4)" ::: "memory"); }
            else            { asm volatile("s_waitcnt vmcnt(0)" ::: "memory"); }
            __builtin_amdgcn_sched_barrier(0);
            __builtin_amdgcn_s_barrier();
        }
    }
#undef STAGE_A
#undef STAGE_B

    #pragma unroll
    for (int n = 0; n < 4; ++n) {
        int e = n0 + wc * 64 + n * 16 + r16;
        float bb = bo[e];
        #pragma unroll
        for (int m = 0; m < 4; ++m) {
            #pragma unroll
            for (int r = 0; r < 4; ++r) {
                int tok = m0 + wr * 64 + m * 16 + kq * 4 + r;
                out[(size_t)tok * E_DIM + e] = acc[m][n][r] + bb;
            }
        }
    }
}

// ---------------- sliding-window flash attention: 32 q-rows per wave ----------------
// MODE: 0 = interior (no mask), 1 = head tile (key < qrow-WIN masked), 2 = tail (key > qrow masked)
template<int MODE, bool PRE>
__device__ __forceinline__ void attn_tile(int k0,
        const unsigned short* __restrict__ kp, const unsigned short* __restrict__ vp,
        int r16, int kq, char* pl,
        const short8 (&qf)[2][2], short8 (&kf)[2][2],
        f32x4 (&po)[2][4], float (&mrow)[2][4], float (&lsum)[2][4]) {
    f32x4 sc[2][2];
    #pragma unroll
    for (int mf = 0; mf < 2; ++mf)
        #pragma unroll
        for (int n = 0; n < 2; ++n) {
            f32x4 z = {0.f, 0.f, 0.f, 0.f};
            z = __builtin_amdgcn_mfma_f32_16x16x32_bf16(qf[mf][0], kf[n][0], z, 0, 0, 0);
            sc[mf][n] = __builtin_amdgcn_mfma_f32_16x16x32_bf16(qf[mf][1], kf[n][1], z, 0, 0, 0);
        }
    if (PRE) {
        #pragma unroll
        for (int n = 0; n < 2; ++n) {
            const unsigned short* kr = kp + (size_t)(k0 + 32 + n * 16 + r16) * HDIM + kq * 8;
            kf[n][0] = *(const short8*)(kr);
            kf[n][1] = *(const short8*)(kr + 32);
        }
    }
    short8 vf[4];
    #pragma unroll
    for (int nn = 0; nn < 4; ++nn)
        vf[nn] = *(const short8*)(vp + (size_t)(nn * 16 + r16) * SEQ + k0 + kq * 8);

    float tmax[2][4];
    #pragma unroll
    for (int mf = 0; mf < 2; ++mf)
        #pragma unroll
        for (int r = 0; r < 4; ++r) {
            int rel = mf * 16 + kq * 4 + r;
            if (MODE == 1) {
                if (r16 < rel)      sc[mf][0][r] = -1e30f;
                if (16 + r16 < rel) sc[mf][1][r] = -1e30f;
            }
            if (MODE == 2) {
                if (r16 > rel)      sc[mf][0][r] = -1e30f;
                if (16 + r16 > rel) sc[mf][1][r] = -1e30f;
            }
            tmax[mf][r] = fmaxf(sc[mf][0][r], sc[mf][1][r]);
        }
    #pragma unroll
    for (int off = 1; off < 16; off <<= 1)
        #pragma unroll
        for (int mf = 0; mf < 2; ++mf)
            #pragma unroll
            for (int r = 0; r < 4; ++r)
                tmax[mf][r] = fmaxf(tmax[mf][r], __shfl_xor(tmax[mf][r], off));
    float pv[2][2][4];
    #pragma unroll
    for (int mf = 0; mf < 2; ++mf)
        #pragma unroll
        for (int r = 0; r < 4; ++r) {
            float mnew = fmaxf(mrow[mf][r], tmax[mf][r]);
            float resc = __expf(mrow[mf][r] - mnew);
            mrow[mf][r] = mnew;
            float p0 = __expf(sc[mf][0][r] - mnew);
            float p1 = __expf(sc[mf][1][r] - mnew);
            lsum[mf][r] = lsum[mf][r] * resc + p0 + p1;
            po[mf][0][r] *= resc; po[mf][1][r] *= resc;
            po[mf][2][r] *= resc; po[mf][3][r] *= resc;
            pv[mf][0][r] = p0; pv[mf][1][r] = p1;
        }
    #pragma unroll
    for (int mf = 0; mf < 2; ++mf)
        #pragma unroll
        for (int r = 0; r < 4; ++r) {
            int row = kq * 4 + r;
            int c0 = r16 ^ ((row & 7) << 3);
            int c1 = c0 ^ 16;
            *(unsigned short*)(pl + mf * 2048 + row * 128 + c0 * 2) = f2bf(pv[mf][0][r]);
            *(unsigned short*)(pl + mf * 2048 + row * 128 + c1 * 2) = f2bf(pv[mf][1][r]);
        }
    short8 pa[2];
    #pragma unroll
    for (int mf = 0; mf < 2; ++mf)
        pa[mf] = *(const short8*)(pl + mf * 2048 + r16 * 128 + ((kq ^ (r16 & 7)) * 16));
    #pragma unroll
    for (int nn = 0; nn < 4; ++nn) {
        po[0][nn] = __builtin_amdgcn_mfma_f32_16x16x32_bf16(pa[0], vf[nn], po[0][nn], 0, 0, 0);
        po[1][nn] = __builtin_amdgcn_mfma_f32_16x16x32_bf16(pa[1], vf[nn], po[1][nn], 0, 0, 0);
    }
}

__global__ __launch_bounds__(256) void attn_swa(const unsigned short* __restrict__ q,
                                                const unsigned short* __restrict__ k,
                                                const unsigned short* __restrict__ vT,
                                                unsigned short* __restrict__ y) {
    __shared__ char plds[4 * 4096];
    const int t = threadIdx.x;
    const int w = t >> 6, l = t & 63;
    const int r16 = l & 15, kq = l >> 4;
    const int wid = blockIdx.x * 4 + w;
    const int bh = wid >> 6;
    const int q0 = (wid & 63) * 32;
    const unsigned short* qp = q + (size_t)bh * SEQ * HDIM;
    const unsigned short* kp = k + (size_t)bh * SEQ * HDIM;
    const unsigned short* vp = vT + (size_t)bh * HDIM * SEQ;
    char* pl = plds + w * 4096;

    short8 qf[2][2];
    #pragma unroll
    for (int mf = 0; mf < 2; ++mf) {
        const unsigned short* qr = qp + (q0 + mf * 16 + r16) * HDIM + kq * 8;
        qf[mf][0] = *(const short8*)(qr);
        qf[mf][1] = *(const short8*)(qr + 32);
    }

    f32x4 po[2][4];
    float mrow[2][4], lsum[2][4];
    #pragma unroll
    for (int mf = 0; mf < 2; ++mf) {
        #pragma unroll
        for (int nn = 0; nn < 4; ++nn) po[mf][nn] = (f32x4){0.f, 0.f, 0.f, 0.f};
        #pragma unroll
        for (int r = 0; r < 4; ++r) { mrow[mf][r] = -1e30f; lsum[mf][r] = 0.f; }
    }

    const int kstart = (q0 >= WIN) ? (q0 - WIN) : 0;
    short8 kf[2][2];
    #pragma unroll
    for (int n = 0; n < 2; ++n) {
        const unsigned short* kr = kp + (size_t)(kstart + n * 16 + r16) * HDIM + kq * 8;
        kf[n][0] = *(const short8*)(kr);
        kf[n][1] = *(const short8*)(kr + 32);
    }

    int k0 = kstart;
    if (q0 >= WIN) {
        attn_tile<1, true>(k0, kp, vp, r16, kq, pl, qf, kf, po, mrow, lsum);
        k0 += 32;
    }
    for (; k0 < q0; k0 += 32)
        attn_tile<0, true>(k0, kp, vp, r16, kq, pl, qf, kf, po, mrow, lsum);
    attn_tile<2, false>(q0, kp, vp, r16, kq, pl, qf, kf, po, mrow, lsum);

    #pragma unroll
    for (int off = 1; off < 16; off <<= 1)
        #pragma unroll
        for (int mf = 0; mf < 2; ++mf)
            #pragma unroll
            for (int r = 0; r < 4; ++r)
                lsum[mf][r] += __shfl_xor(lsum[mf][r], off);

    const int b = bh >> 4, h = bh & 15;
    #pragma unroll
    for (int mf = 0; mf < 2; ++mf)
        #pragma unroll
        for (int nn = 0; nn < 4; ++nn)
            #pragma unroll
            for (int r = 0; r < 4; ++r) {
                int s = q0 + mf * 16 + kq * 4 + r;
                float val = po[mf][nn][r] / lsum[mf][r];
                y[((size_t)(b * SEQ + s)) * E_DIM + h * HDIM + nn * 16 + r16] = f2bf(val);
            }
}

extern "C" void kernel_launch(void* const* d_in, const int* in_sizes, int n_in,
                              void* d_out, int out_size, void* d_ws, size_t ws_size,
                              hipStream_t stream) {
    const float* x  = (const float*)d_in[0];
    const float* Wq = (const float*)d_in[1];
    const float* Wk = (const float*)d_in[2];
    const float* Wv = (const float*)d_in[3];
    const float* Wo = (const float*)d_in[4];
    const float* bq = (const float*)d_in[5];
    const float* bk = (const float*)d_in[6];
    const float* bv = (const float*)d_in[7];
    const float* bo = (const float*)d_in[8];
    float* out = (float*)d_out;

    char* ws = (char*)d_ws;
    unsigned short* xb  = (unsigned short*)(ws);                        // 8 MB
    unsigned short* wqb = (unsigned short*)(ws + ((size_t)8 << 20));    // 2 MB
    unsigned short* wkb = (unsigned short*)(ws + ((size_t)10 << 20));   // 2 MB
    unsigned short* wvb = (unsigned short*)(ws + ((size_t)12 << 20));   // 2 MB
    unsigned short* wob = (unsigned short*)(ws + ((size_t)14 << 20));   // 2 MB
    unsigned short* qw  = (unsigned short*)(ws + ((size_t)16 << 20));   // 8 MB
    unsigned short* kw  = (unsigned short*)(ws + ((size_t)24 << 20));   // 8 MB
    unsigned short* vTw = (unsigned short*)(ws + ((size_t)40 << 20));   // 8 MB
    unsigned short* yw  = (unsigned short*)(ws + ((size_t)48 << 20));   // 8 MB

    conv_all<<<dim3(1024, 8), 256, 0, stream>>>(x, Wq, Wk, Wv, Wo, xb, wqb, wkb, wvb, wob);

    gemm97_qkv<<<dim3(32, 24), 256, 0, stream>>>(xb, wqb, wkb, wvb, bq, bk, bv, qw, kw, vTw);
    attn_swa<<<512, 256, 0, stream>>>(qw, kw, vTw, yw);
    gemm_out<<<dim3(32, 8), 256, 0, stream>>>(yw, wob, bo, out);
}

// Round 9
// 162.816 us; speedup vs baseline: 1.0075x; 1.0075x over previous
//
#include <hip/hip_runtime.h>

#define E_DIM 1024
#define NHEAD 16
#define HDIM 64
#define SEQ 2048
#define NBATCH 2
#define WIN 256
#define MTOK (NBATCH * SEQ) // 4096
#define BKT 32              // K per pipeline tile
#define NT (E_DIM / BKT)    // 32 tiles

typedef __attribute__((ext_vector_type(4))) float f32x4;
typedef __attribute__((ext_vector_type(8))) short short8;
typedef __attribute__((ext_vector_type(4))) unsigned short u16x4;

#define AS1 __attribute__((address_space(1)))
#define AS3 __attribute__((address_space(3)))

__device__ __forceinline__ void gll16(const void* g, void* l) {
    __builtin_amdgcn_global_load_lds((const AS1 void*)g, (AS3 void*)l, 16, 0, 0);
}

__device__ __forceinline__ unsigned short f2bf(float f) {
    union { float f; unsigned u; } a; a.f = f;
    unsigned r = a.u + 0x7fffu + ((a.u >> 16) & 1u);
    return (unsigned short)(r >> 16);
}

// ---------------- fused fp32 -> bf16 conversion: x (4 segs) + 4 weights ----------------
__global__ __launch_bounds__(256) void conv_all(const float* __restrict__ x,
        const float* __restrict__ w0, const float* __restrict__ w1,
        const float* __restrict__ w2, const float* __restrict__ w3,
        unsigned short* __restrict__ xo,
        unsigned short* __restrict__ o0, unsigned short* __restrict__ o1,
        unsigned short* __restrict__ o2, unsigned short* __restrict__ o3) {
    const int seg = blockIdx.y;   // 0..3: x quarters; 4..7: weights
    const float* src;
    unsigned short* dst;
    if (seg < 4) { src = x + (size_t)seg * 1048576; dst = xo + (size_t)seg * 1048576; }
    else {
        src = (seg == 4) ? w0 : (seg == 5) ? w1 : (seg == 6) ? w2 : w3;
        dst = (seg == 4) ? o0 : (seg == 5) ? o1 : (seg == 6) ? o2 : o3;
    }
    int i = blockIdx.x * 256 + threadIdx.x;
    float4 v = ((const float4*)src)[i];
    u16x4 o;
    o[0] = f2bf(v.x); o[1] = f2bf(v.y); o[2] = f2bf(v.z); o[3] = f2bf(v.w);
    ((u16x4*)dst)[i] = o;
}

// ---------------- QKV GEMM: m97 geometry (r8, proven) + coalesced epilogue ----------------
// Q,K written token-major [tok][e] (full-line stores). V written as vT via per-wave
// 64x64 LDS-bounce transpose (each lane stores one full 128B vT row).
__global__ __launch_bounds__(256, 3) void gemm97_qkv(const unsigned short* __restrict__ xb,
        const unsigned short* __restrict__ wqb, const unsigned short* __restrict__ wkb,
        const unsigned short* __restrict__ wvb,
        const float* __restrict__ bq, const float* __restrict__ bk, const float* __restrict__ bv,
        unsigned short* __restrict__ qo, unsigned short* __restrict__ ko,
        unsigned short* __restrict__ vTo) {
    __shared__ char lds[32768];           // 2 slots x (A 8KB + B 8KB); reused for V transpose
    const int tid = threadIdx.x;
    const int w = tid >> 6, l = tid & 63;
    const int r16 = l & 15, kq = l >> 4;
    const int wr = w >> 1, wc = w & 1;    // 2x2 waves, each 64x64 out
    const int m0 = blockIdx.x * 128;
    const int by = blockIdx.y;            // 0..23
    const int mat = by >> 3;              // 0:Q 1:K 2:V
    const int nb = (by & 7) * 128;
    const unsigned short* Bw = (mat == 0) ? wqb : (mat == 1) ? wkb : wvb;

    const int srow = tid >> 2;            // 0..63
    const int sslot = tid & 3;
    const int fsw = (srow >> 1) & 3;
    const int gslot = (sslot ^ fsw) * 8;  // pre-swizzled source slot (elements)
    const unsigned short* aSrc0 = xb + (size_t)(m0 + srow) * E_DIM + gslot;
    const unsigned short* aSrc1 = aSrc0 + (size_t)64 * E_DIM;
    const unsigned short* bSrc0 = Bw + (size_t)(nb + srow) * E_DIM + gslot;
    const unsigned short* bSrc1 = bSrc0 + (size_t)64 * E_DIM;
    const int dstOff = w * 1024;

#define STAGE(t) { char* a_ = lds + ((t) & 1) * 16384 + dstOff; \
                   char* b_ = a_ + 8192; \
                   gll16(aSrc0 + (t) * BKT, a_); gll16(aSrc1 + (t) * BKT, a_ + 4096); \
                   gll16(bSrc0 + (t) * BKT, b_); gll16(bSrc1 + (t) * BKT, b_ + 4096); }

    f32x4 acc[4][4];
    #pragma unroll
    for (int m = 0; m < 4; ++m)
        #pragma unroll
        for (int n = 0; n < 4; ++n)
            acc[m][n] = (f32x4){0.f, 0.f, 0.f, 0.f};

    STAGE(0);

    const int fs = (r16 >> 1) & 3;
    const int rdoff = (kq ^ fs) * 16;

    for (int t = 0; t < NT; ++t) {
        __syncthreads();                  // implicit vmcnt(0): stage(t) landed for ALL waves
        if (t + 1 < NT) STAGE(t + 1);
        char* la = lds + (t & 1) * 16384;
        char* lb = la + 8192;
        short8 af[4], bfr[4];
        #pragma unroll
        for (int m = 0; m < 4; ++m)
            af[m] = *(const short8*)(la + (wr * 64 + m * 16 + r16) * 64 + rdoff);
        #pragma unroll
        for (int n = 0; n < 4; ++n)
            bfr[n] = *(const short8*)(lb + (wc * 64 + n * 16 + r16) * 64 + rdoff);
        __builtin_amdgcn_s_setprio(1);
        #pragma unroll
        for (int m = 0; m < 4; ++m)
            #pragma unroll
            for (int n = 0; n < 4; ++n)
                acc[m][n] = __builtin_amdgcn_mfma_f32_16x16x32_bf16(af[m], bfr[n], acc[m][n], 0, 0, 0);
        __builtin_amdgcn_s_setprio(0);
    }
#undef STAGE

    __syncthreads();                      // all waves done with staging LDS (reuse for V bounce)

    const float* bias = (mat == 0) ? bq : (mat == 1) ? bk : bv;
    if (mat != 2) {
        // Q/K token-major: dst[tok][e] — wave's 4 n-frags cover 128 contiguous bytes per row
        unsigned short* dst = (mat == 0) ? qo : ko;
        const float scale = (mat == 0) ? 0.125f : 1.0f;   // D^-0.5 folded into Q
        #pragma unroll
        for (int n = 0; n < 4; ++n) {
            int e = nb + wc * 64 + n * 16 + r16;
            float bb = bias[e];
            #pragma unroll
            for (int m = 0; m < 4; ++m) {
                int tokb = m0 + wr * 64 + m * 16 + kq * 4;
                #pragma unroll
                for (int r = 0; r < 4; ++r)
                    dst[(size_t)(tokb + r) * E_DIM + e] = f2bf((acc[m][n][r] + bb) * scale);
            }
        }
    } else {
        // V: per-wave 64x64 transpose through LDS, then full-row coalesced vT stores
        char* pl = lds + w * 8192;        // 64 rows x 128 B
        #pragma unroll
        for (int n = 0; n < 4; ++n) {
            int e = nb + wc * 64 + n * 16 + r16;
            float bb = bias[e];
            int d = n * 16 + r16;         // 0..63 within this wave's head
            #pragma unroll
            for (int m = 0; m < 4; ++m) {
                int s0 = m * 16 + kq * 4; // 0..63, multiple of 4
                u16x4 o;
                #pragma unroll
                for (int r = 0; r < 4; ++r) o[r] = f2bf(acc[m][n][r] + bb);
                *(u16x4*)(pl + d * 128 + (((s0 >> 3) ^ (d & 7)) * 16) + (s0 & 7) * 2) = o;
            }
        }
        const int h = (nb + wc * 64) >> 6;
        const int b = m0 >> 11;
        const int sbase = (m0 & (SEQ - 1)) + wr * 64;
        const int dd = l;                 // lane <-> d row, 0..63
        unsigned short* vrow = vTo + ((size_t)(b * NHEAD + h) * HDIM + dd) * SEQ + sbase;
        #pragma unroll
        for (int c = 0; c < 8; ++c)
            *(short8*)(vrow + c * 8) = *(const short8*)(pl + dd * 128 + ((c ^ (dd & 7)) * 16));
    }
}

// ---------------- output projection: 128x64 tiles, 512 blocks = 2/CU, r8 structure ----------------
__global__ __launch_bounds__(256, 2) void gemm_out(const unsigned short* __restrict__ yb,
        const unsigned short* __restrict__ wob, const float* __restrict__ bo,
        float* __restrict__ out) {
    __shared__ char lds[24576];           // 2 slots x (A 8KB + B 4KB)
    const int tid = threadIdx.x;
    const int w = tid >> 6, l = tid & 63;
    const int r16 = l & 15, kq = l >> 4;
    const int wr = w >> 1, wc = w & 1;    // per-wave 64(M) x 32(N)
    const int m0 = blockIdx.x * 128;
    const int n0 = blockIdx.y * 64;

    const int srow = tid >> 2;            // 0..63
    const int sslot = tid & 3;
    const int fsw = (srow >> 1) & 3;
    const int gslot = (sslot ^ fsw) * 8;
    const unsigned short* aSrc0 = yb + (size_t)(m0 + srow) * E_DIM + gslot;
    const unsigned short* aSrc1 = aSrc0 + (size_t)64 * E_DIM;
    const unsigned short* bSrc0 = wob + (size_t)(n0 + srow) * E_DIM + gslot;
    const int dstOff = w * 1024;

#define STAGE(t) { char* a_ = lds + ((t) & 1) * 12288 + dstOff; \
                   gll16(aSrc0 + (t) * BKT, a_); gll16(aSrc1 + (t) * BKT, a_ + 4096); \
                   gll16(bSrc0 + (t) * BKT, a_ + (8192 - dstOff) + dstOff); }

    f32x4 acc[4][2];
    #pragma unroll
    for (int m = 0; m < 4; ++m)
        #pragma unroll
        for (int n = 0; n < 2; ++n)
            acc[m][n] = (f32x4){0.f, 0.f, 0.f, 0.f};

    STAGE(0);

    const int fs = (r16 >> 1) & 3;
    const int rdoff = (kq ^ fs) * 16;

    for (int t = 0; t < NT; ++t) {
        __syncthreads();
        if (t + 1 < NT) STAGE(t + 1);
        char* la = lds + (t & 1) * 12288;
        char* lb = la + 8192;
        short8 af[4], bfr[2];
        #pragma unroll
        for (int m = 0; m < 4; ++m)
            af[m] = *(const short8*)(la + (wr * 64 + m * 16 + r16) * 64 + rdoff);
        #pragma unroll
        for (int n = 0; n < 2; ++n)
            bfr[n] = *(const short8*)(lb + (wc * 32 + n * 16 + r16) * 64 + rdoff);
        __builtin_amdgcn_s_setprio(1);
        #pragma unroll
        for (int m = 0; m < 4; ++m)
            #pragma unroll
            for (int n = 0; n < 2; ++n)
                acc[m][n] = __builtin_amdgcn_mfma_f32_16x16x32_bf16(af[m], bfr[n], acc[m][n], 0, 0, 0);
        __builtin_amdgcn_s_setprio(0);
    }
#undef STAGE

    #pragma unroll
    for (int n = 0; n < 2; ++n) {
        int e = n0 + wc * 32 + n * 16 + r16;
        float bb = bo[e];
        #pragma unroll
        for (int m = 0; m < 4; ++m) {
            #pragma unroll
            for (int r = 0; r < 4; ++r) {
                int tok = m0 + wr * 64 + m * 16 + kq * 4 + r;
                out[(size_t)tok * E_DIM + e] = acc[m][n][r] + bb;
            }
        }
    }
}

// ---------------- sliding-window flash attention: 32 q-rows per wave ----------------
// Q,K now token-major [tok][e]: row stride E_DIM, head offset h*HDIM.
// MODE: 0 = interior (no mask), 1 = head tile, 2 = tail (causal)
template<int MODE, bool PRE>
__device__ __forceinline__ void attn_tile(int k0,
        const unsigned short* __restrict__ kp, const unsigned short* __restrict__ vp,
        int r16, int kq, char* pl,
        const short8 (&qf)[2][2], short8 (&kf)[2][2],
        f32x4 (&po)[2][4], float (&mrow)[2][4], float (&lsum)[2][4]) {
    f32x4 sc[2][2];
    #pragma unroll
    for (int mf = 0; mf < 2; ++mf)
        #pragma unroll
        for (int n = 0; n < 2; ++n) {
            f32x4 z = {0.f, 0.f, 0.f, 0.f};
            z = __builtin_amdgcn_mfma_f32_16x16x32_bf16(qf[mf][0], kf[n][0], z, 0, 0, 0);
            sc[mf][n] = __builtin_amdgcn_mfma_f32_16x16x32_bf16(qf[mf][1], kf[n][1], z, 0, 0, 0);
        }
    if (PRE) {
        #pragma unroll
        for (int n = 0; n < 2; ++n) {
            const unsigned short* kr = kp + (size_t)(k0 + 32 + n * 16 + r16) * E_DIM + kq * 8;
            kf[n][0] = *(const short8*)(kr);
            kf[n][1] = *(const short8*)(kr + 32);
        }
    }
    short8 vf[4];
    #pragma unroll
    for (int nn = 0; nn < 4; ++nn)
        vf[nn] = *(const short8*)(vp + (size_t)(nn * 16 + r16) * SEQ + k0 + kq * 8);

    float tmax[2][4];
    #pragma unroll
    for (int mf = 0; mf < 2; ++mf)
        #pragma unroll
        for (int r = 0; r < 4; ++r) {
            int rel = mf * 16 + kq * 4 + r;
            if (MODE == 1) {
                if (r16 < rel)      sc[mf][0][r] = -1e30f;
                if (16 + r16 < rel) sc[mf][1][r] = -1e30f;
            }
            if (MODE == 2) {
                if (r16 > rel)      sc[mf][0][r] = -1e30f;
                if (16 + r16 > rel) sc[mf][1][r] = -1e30f;
            }
            tmax[mf][r] = fmaxf(sc[mf][0][r], sc[mf][1][r]);
        }
    #pragma unroll
    for (int off = 1; off < 16; off <<= 1)
        #pragma unroll
        for (int mf = 0; mf < 2; ++mf)
            #pragma unroll
            for (int r = 0; r < 4; ++r)
                tmax[mf][r] = fmaxf(tmax[mf][r], __shfl_xor(tmax[mf][r], off));
    float pv[2][2][4];
    #pragma unroll
    for (int mf = 0; mf < 2; ++mf)
        #pragma unroll
        for (int r = 0; r < 4; ++r) {
            float mnew = fmaxf(mrow[mf][r], tmax[mf][r]);
            float resc = __expf(mrow[mf][r] - mnew);
            mrow[mf][r] = mnew;
            float p0 = __expf(sc[mf][0][r] - mnew);
            float p1 = __expf(sc[mf][1][r] - mnew);
            lsum[mf][r] = lsum[mf][r] * resc + p0 + p1;
            po[mf][0][r] *= resc; po[mf][1][r] *= resc;
            po[mf][2][r] *= resc; po[mf][3][r] *= resc;
            pv[mf][0][r] = p0; pv[mf][1][r] = p1;
        }
    #pragma unroll
    for (int mf = 0; mf < 2; ++mf)
        #pragma unroll
        for (int r = 0; r < 4; ++r) {
            int row = kq * 4 + r;
            int c0 = r16 ^ ((row & 7) << 3);
            int c1 = c0 ^ 16;
            *(unsigned short*)(pl + mf * 2048 + row * 128 + c0 * 2) = f2bf(pv[mf][0][r]);
            *(unsigned short*)(pl + mf * 2048 + row * 128 + c1 * 2) = f2bf(pv[mf][1][r]);
        }
    short8 pa[2];
    #pragma unroll
    for (int mf = 0; mf < 2; ++mf)
        pa[mf] = *(const short8*)(pl + mf * 2048 + r16 * 128 + ((kq ^ (r16 & 7)) * 16));
    #pragma unroll
    for (int nn = 0; nn < 4; ++nn) {
        po[0][nn] = __builtin_amdgcn_mfma_f32_16x16x32_bf16(pa[0], vf[nn], po[0][nn], 0, 0, 0);
        po[1][nn] = __builtin_amdgcn_mfma_f32_16x16x32_bf16(pa[1], vf[nn], po[1][nn], 0, 0, 0);
    }
}

__global__ __launch_bounds__(256) void attn_swa(const unsigned short* __restrict__ q,
                                                const unsigned short* __restrict__ k,
                                                const unsigned short* __restrict__ vT,
                                                unsigned short* __restrict__ y) {
    __shared__ char plds[4 * 4096];
    const int t = threadIdx.x;
    const int w = t >> 6, l = t & 63;
    const int r16 = l & 15, kq = l >> 4;
    const int wid = blockIdx.x * 4 + w;
    const int bh = wid >> 6;
    const int q0 = (wid & 63) * 32;
    const int b = bh >> 4, h = bh & 15;
    const unsigned short* qp = q + (size_t)b * SEQ * E_DIM + h * HDIM;
    const unsigned short* kp = k + (size_t)b * SEQ * E_DIM + h * HDIM;
    const unsigned short* vp = vT + (size_t)bh * HDIM * SEQ;
    char* pl = plds + w * 4096;

    short8 qf[2][2];
    #pragma unroll
    for (int mf = 0; mf < 2; ++mf) {
        const unsigned short* qr = qp + (size_t)(q0 + mf * 16 + r16) * E_DIM + kq * 8;
        qf[mf][0] = *(const short8*)(qr);
        qf[mf][1] = *(const short8*)(qr + 32);
    }

    f32x4 po[2][4];
    float mrow[2][4], lsum[2][4];
    #pragma unroll
    for (int mf = 0; mf < 2; ++mf) {
        #pragma unroll
        for (int nn = 0; nn < 4; ++nn) po[mf][nn] = (f32x4){0.f, 0.f, 0.f, 0.f};
        #pragma unroll
        for (int r = 0; r < 4; ++r) { mrow[mf][r] = -1e30f; lsum[mf][r] = 0.f; }
    }

    const int kstart = (q0 >= WIN) ? (q0 - WIN) : 0;
    short8 kf[2][2];
    #pragma unroll
    for (int n = 0; n < 2; ++n) {
        const unsigned short* kr = kp + (size_t)(kstart + n * 16 + r16) * E_DIM + kq * 8;
        kf[n][0] = *(const short8*)(kr);
        kf[n][1] = *(const short8*)(kr + 32);
    }

    int k0 = kstart;
    if (q0 >= WIN) {
        attn_tile<1, true>(k0, kp, vp, r16, kq, pl, qf, kf, po, mrow, lsum);
        k0 += 32;
    }
    for (; k0 < q0; k0 += 32)
        attn_tile<0, true>(k0, kp, vp, r16, kq, pl, qf, kf, po, mrow, lsum);
    attn_tile<2, false>(q0, kp, vp, r16, kq, pl, qf, kf, po, mrow, lsum);

    #pragma unroll
    for (int off = 1; off < 16; off <<= 1)
        #pragma unroll
        for (int mf = 0; mf < 2; ++mf)
            #pragma unroll
            for (int r = 0; r < 4; ++r)
                lsum[mf][r] += __shfl_xor(lsum[mf][r], off);

    #pragma unroll
    for (int mf = 0; mf < 2; ++mf)
        #pragma unroll
        for (int nn = 0; nn < 4; ++nn)
            #pragma unroll
            for (int r = 0; r < 4; ++r) {
                int s = q0 + mf * 16 + kq * 4 + r;
                float val = po[mf][nn][r] / lsum[mf][r];
                y[((size_t)(b * SEQ + s)) * E_DIM + h * HDIM + nn * 16 + r16] = f2bf(val);
            }
}

extern "C" void kernel_launch(void* const* d_in, const int* in_sizes, int n_in,
                              void* d_out, int out_size, void* d_ws, size_t ws_size,
                              hipStream_t stream) {
    const float* x  = (const float*)d_in[0];
    const float* Wq = (const float*)d_in[1];
    const float* Wk = (const float*)d_in[2];
    const float* Wv = (const float*)d_in[3];
    const float* Wo = (const float*)d_in[4];
    const float* bq = (const float*)d_in[5];
    const float* bk = (const float*)d_in[6];
    const float* bv = (const float*)d_in[7];
    const float* bo = (const float*)d_in[8];
    float* out = (float*)d_out;

    char* ws = (char*)d_ws;
    unsigned short* xb  = (unsigned short*)(ws);                        // 8 MB
    unsigned short* wqb = (unsigned short*)(ws + ((size_t)8 << 20));    // 2 MB
    unsigned short* wkb = (unsigned short*)(ws + ((size_t)10 << 20));   // 2 MB
    unsigned short* wvb = (unsigned short*)(ws + ((size_t)12 << 20));   // 2 MB
    unsigned short* wob = (unsigned short*)(ws + ((size_t)14 << 20));   // 2 MB
    unsigned short* qw  = (unsigned short*)(ws + ((size_t)16 << 20));   // 8 MB token-major
    unsigned short* kw  = (unsigned short*)(ws + ((size_t)24 << 20));   // 8 MB token-major
    unsigned short* vTw = (unsigned short*)(ws + ((size_t)40 << 20));   // 8 MB (bh,d,s)
    unsigned short* yw  = (unsigned short*)(ws + ((size_t)48 << 20));   // 8 MB

    conv_all<<<dim3(1024, 8), 256, 0, stream>>>(x, Wq, Wk, Wv, Wo, xb, wqb, wkb, wvb, wob);

    gemm97_qkv<<<dim3(32, 24), 256, 0, stream>>>(xb, wqb, wkb, wvb, bq, bk, bv, qw, kw, vTw);
    attn_swa<<<512, 256, 0, stream>>>(qw, kw, vTw, yw);
    gemm_out<<<dim3(32, 16), 256, 0, stream>>>(yw, wob, bo, out);
}